// Round 1
// baseline (312.488 us; speedup 1.0000x reference)
//
#include <hip/hip_runtime.h>
#include <math.h>

// Octonion product via Cayley-Dickson over quaternions (matches reference's
// _oct_structure exactly, so no hand-transcribed 8x8x8 table to get wrong).
__device__ __forceinline__ void qmul(float w1, float x1, float y1, float z1,
                                     float w2, float x2, float y2, float z2,
                                     float& w, float& x, float& y, float& z) {
    w = w1 * w2 - x1 * x2 - y1 * y2 - z1 * z2;
    x = w1 * x2 + x1 * w2 + y1 * z2 - z1 * y2;
    y = w1 * y2 - x1 * z2 + y1 * w2 + z1 * x2;
    z = w1 * z2 + x1 * y2 - y1 * x2 + z1 * w2;
}

__global__ __launch_bounds__(256) void oct_fano_kernel(
    const float* __restrict__ in,    // (B, 7, 8) fp32
    const float* __restrict__ logs,  // scalar log_sensitivity
    float* __restrict__ out,         // (B,) fp32
    int B) {
    int b = blockIdx.x * 256 + threadIdx.x;
    if (b >= B) return;

    float x[7][8];
    // 14 float4 loads = 224B contiguous per thread (16B-aligned: 56*4 % 16 == 0)
    const float4* p = (const float4*)(in + (size_t)b * 56);
#pragma unroll
    for (int k = 0; k < 14; k++) {
        float4 v = p[k];
        int r = k >> 1;
        int c = (k & 1) * 4;
        x[r][c + 0] = v.x;
        x[r][c + 1] = v.y;
        x[r][c + 2] = v.z;
        x[r][c + 3] = v.w;
    }

    // Normalize each of the 7 rows (norm = max(||x||, 1e-12))
#pragma unroll
    for (int r = 0; r < 7; r++) {
        float s = 0.f;
#pragma unroll
        for (int c = 0; c < 8; c++) s += x[r][c] * x[r][c];
        float n = fmaxf(sqrtf(s), 1e-12f);
        float inv = 1.0f / n;
#pragma unroll
        for (int c = 0; c < 8; c++) x[r][c] *= inv;
    }

    // 7 Fano lines: (i, j, k) = (l, (l+1)%7, (l+3)%7)
    float total = 0.f;
#pragma unroll
    for (int l = 0; l < 7; l++) {
        const float* a = x[l];
        const float* bb = x[(l + 1) % 7];
        const float* ck = x[(l + 3) % 7];

        float p0, p1, p2, p3, p4, p5, p6, p7;
        float t0, t1, t2, t3;
        // c1 = qmul(a1, b1) - qmul(conj(b2), a2)
        qmul(a[0], a[1], a[2], a[3], bb[0], bb[1], bb[2], bb[3], p0, p1, p2, p3);
        qmul(bb[4], -bb[5], -bb[6], -bb[7], a[4], a[5], a[6], a[7], t0, t1, t2, t3);
        p0 -= t0; p1 -= t1; p2 -= t2; p3 -= t3;
        // c2 = qmul(b2, a1) + qmul(a2, conj(b1))
        qmul(bb[4], bb[5], bb[6], bb[7], a[0], a[1], a[2], a[3], p4, p5, p6, p7);
        qmul(a[4], a[5], a[6], a[7], bb[0], -bb[1], -bb[2], -bb[3], t0, t1, t2, t3);
        p4 += t0; p5 += t1; p6 += t2; p7 += t3;

        float d0 = p0 - ck[0], d1 = p1 - ck[1], d2 = p2 - ck[2], d3 = p3 - ck[3];
        float d4 = p4 - ck[4], d5 = p5 - ck[5], d6 = p6 - ck[6], d7 = p7 - ck[7];
        total += d0 * d0 + d1 * d1 + d2 * d2 + d3 * d3 +
                 d4 * d4 + d5 * d5 + d6 * d6 + d7 * d7;
    }

    float avg = total * (1.0f / 7.0f);
    float phi = -logf(avg + 1e-8f) * expf(logs[0]);
    phi = fminf(fmaxf(phi, 0.0f), 10.0f);
    out[b] = phi;
}

extern "C" void kernel_launch(void* const* d_in, const int* in_sizes, int n_in,
                              void* d_out, int out_size, void* d_ws, size_t ws_size,
                              hipStream_t stream) {
    const float* states = (const float*)d_in[0];
    const float* logs = (const float*)d_in[1];
    float* out = (float*)d_out;
    int B = in_sizes[0] / 56;  // 7*8 floats per batch
    int blocks = (B + 255) / 256;
    oct_fano_kernel<<<blocks, 256, 0, stream>>>(states, logs, out, B);
}